// Round 11
// baseline (283.812 us; speedup 1.0000x reference)
//
#include <hip/hip_runtime.h>

// out[..., m] = b[..., m] + ALPHA * b[..., m+1]  (m < 39);  out[..., 39] = b[..., 39]
// b: (16, 65536, 40) float32, flat n = 41,943,040 = 10,485,760 float4s.
// Row = 40 floats = 10 float4s -> within a float4 (index i) only elem 3 can be
// the row-last coeff, exactly when i % 10 == 9.
//
// R10 (resubmitted after acquisition timeout): R4's flat-4 shuffle structure
// (measured best, ~75 µs) with the ds_bpermute (__shfl_down) replaced by DPP
// wave_shl:1 — the lane+1 exchange runs in the VALU pipe: no DS op, no lgkmcnt
// wait stage. Evidence (R5/R9): time scales with memory-pipe ops per float4
// (2 VMEM + 1 DS = 75 µs; 3 VMEM = 103 µs; copy's 2 VMEM = 53 µs) — removing
// the DS op should land near the copy roofline. Lane 63 keeps the exec-masked
// fallback load (R4-proven). Normal stores (R3: nontemporal 16B stores halve
// write BW).

static constexpr float kAlpha = 0.42f;
typedef float f32x4 __attribute__((ext_vector_type(4)));

// lane i <- lane i+1 (wave_shl:1, DPP ctrl 0x130); lane 63 gets 0 (bound_ctrl).
__device__ __forceinline__ float dpp_shl1(float x) {
    int r = __builtin_amdgcn_update_dpp(0, __float_as_int(x),
                                        0x130 /*wave_shl:1*/, 0xF, 0xF, true);
    return __int_as_float(r);
}

__global__ void __launch_bounds__(256)
b2mc_kernel(const float* __restrict__ b, float* __restrict__ out, int T) {
    const int t = blockIdx.x * blockDim.x + threadIdx.x;
    if (t >= T) return;
    const f32x4* __restrict__ b4 = reinterpret_cast<const f32x4*>(b);
    f32x4* __restrict__ o4 = reinterpret_cast<f32x4*>(out);

    const int i0 = t;
    const int i1 = t + T;
    const int i2 = t + 2 * T;
    const int i3 = t + 3 * T;

    // 4 independent 16B loads in flight before any dependent work.
    f32x4 v0 = b4[i0];
    f32x4 v1 = b4[i1];
    f32x4 v2 = b4[i2];
    f32x4 v3 = b4[i3];

    // T % 10 == 0 => all four indices share one phase mod 10.
    const bool re = (t % 10) == 9;            // elem 3 is m==39 of its row
    const bool lane63 = ((threadIdx.x & 63) == 63);

    // Neighbor float4's elem 0 from lane+1 via DPP (VALU pipe, no LDS).
    float nxt0 = dpp_shl1(v0.x);
    float nxt1 = dpp_shl1(v1.x);
    float nxt2 = dpp_shl1(v2.x);
    float nxt3 = dpp_shl1(v3.x);
    if (lane63 && !re) {                      // !re => 4*i+4 in bounds (n%40==0)
        nxt0 = b[4 * i0 + 4];
        nxt1 = b[4 * i1 + 4];
        nxt2 = b[4 * i2 + 4];
        nxt3 = b[4 * i3 + 4];
    }

    f32x4 r0, r1, r2, r3;
    r0.x = fmaf(kAlpha, v0.y, v0.x);
    r0.y = fmaf(kAlpha, v0.z, v0.y);
    r0.z = fmaf(kAlpha, v0.w, v0.z);
    r0.w = re ? v0.w : fmaf(kAlpha, nxt0, v0.w);
    r1.x = fmaf(kAlpha, v1.y, v1.x);
    r1.y = fmaf(kAlpha, v1.z, v1.y);
    r1.z = fmaf(kAlpha, v1.w, v1.z);
    r1.w = re ? v1.w : fmaf(kAlpha, nxt1, v1.w);
    r2.x = fmaf(kAlpha, v2.y, v2.x);
    r2.y = fmaf(kAlpha, v2.z, v2.y);
    r2.z = fmaf(kAlpha, v2.w, v2.z);
    r2.w = re ? v2.w : fmaf(kAlpha, nxt2, v2.w);
    r3.x = fmaf(kAlpha, v3.y, v3.x);
    r3.y = fmaf(kAlpha, v3.z, v3.y);
    r3.z = fmaf(kAlpha, v3.w, v3.z);
    r3.w = re ? v3.w : fmaf(kAlpha, nxt3, v3.w);

    o4[i0] = r0;
    o4[i1] = r1;
    o4[i2] = r2;
    o4[i3] = r3;
}

extern "C" void kernel_launch(void* const* d_in, const int* in_sizes, int n_in,
                              void* d_out, int out_size, void* d_ws, size_t ws_size,
                              hipStream_t stream) {
    const float* b = (const float*)d_in[0];
    float* out = (float*)d_out;
    const int n = in_sizes[0];       // 41,943,040
    const int n4 = n / 4;            // 10,485,760 float4s (divisible by 4 and 10)
    const int T = n4 / 4;            // 2,621,440 threads, chunk stride
    const int block = 256;
    const int grid = (T + block - 1) / block;   // 10,240 blocks (exact: grid*256==T)
    b2mc_kernel<<<grid, block, 0, stream>>>(b, out, T);
}